// Round 3
// baseline (459.949 us; speedup 1.0000x reference)
//
#include <hip/hip_runtime.h>

#define CIN  512
#define COUT 512
#define LAT  512
#define NB   16

typedef __attribute__((ext_vector_type(8))) short bf16x8;
typedef __attribute__((ext_vector_type(4))) float f32x4;

__device__ __forceinline__ unsigned short f2bf(float f) {
    unsigned int u = __builtin_bit_cast(unsigned int, f);
    u += 0x7FFFu + ((u >> 16) & 1u);
    return (unsigned short)(u >> 16);
}

// ---------- s[b][ci] = w[b,:] . affine_w[ci,:] + ab[ci] + 1 ----------
__global__ void k_style(const float* __restrict__ w, const float* __restrict__ aw,
                        const float* __restrict__ ab, float* __restrict__ s) {
    int b = blockIdx.x, ci = threadIdx.x;
    __shared__ float wl[LAT];
    wl[ci] = w[b * LAT + ci];
    __syncthreads();
    const float4* awr = (const float4*)(aw + (size_t)ci * LAT);
    float acc = 0.f;
#pragma unroll 4
    for (int l = 0; l < LAT / 4; ++l) {
        float4 a4 = awr[l];
        const float* wp = &wl[l * 4];
        acc += a4.x * wp[0] + a4.y * wp[1] + a4.z * wp[2] + a4.w * wp[3];
    }
    s[b * CIN + ci] = acc + ab[ci] + 1.0f;
}

// ---------- wsq[co][ci] = sum_k weight[co,ci,k]^2 ----------
__global__ void k_wsq(const float* __restrict__ weight, float* __restrict__ wsq) {
    int co = blockIdx.x, ci = threadIdx.x;
    const float* p = weight + ((size_t)co * CIN + ci) * 9;
    float a = 0.f;
#pragma unroll
    for (int k = 0; k < 9; ++k) a += p[k] * p[k];
    wsq[co * CIN + ci] = a;
}

// ---------- d[b][co] = rsqrt(sum_ci s^2 * wsq + 1e-8) ----------
__global__ void k_demod(const float* __restrict__ s, const float* __restrict__ wsq,
                        float* __restrict__ d) {
    int b = blockIdx.x, co = threadIdx.x;
    __shared__ float s2[CIN];
    float sv = s[b * CIN + co];
    s2[co] = sv * sv;
    __syncthreads();
    const float4* wr = (const float4*)(wsq + (size_t)co * CIN);
    float acc = 0.f;
#pragma unroll 4
    for (int i = 0; i < CIN / 4; ++i) {
        float4 v = wr[i];
        const float* sp = &s2[i * 4];
        acc += v.x * sp[0] + v.y * sp[1] + v.z * sp[2] + v.w * sp[3];
    }
    d[b * COUT + co] = rsqrtf(acc + 1e-8f);
}

// ---------- A9[m=co*9+kk][ci] = bf16(weight[co][ci][kk]) ----------
__global__ void k_prepw(const float* __restrict__ weight, unsigned short* __restrict__ A9) {
    int co = blockIdx.x, t = threadIdx.x;
    __shared__ float wl[CIN * 9];
    const float* wp = weight + (size_t)co * CIN * 9;
    for (int i = t; i < CIN * 9; i += 256) wl[i] = wp[i];
    __syncthreads();
    unsigned short* ap = A9 + (size_t)co * 9 * CIN;
    for (int i = t; i < CIN * 9; i += 256) {
        int kk = i >> 9, ci = i & 511;
        ap[i] = f2bf(wl[ci * 9 + kk]);
    }
}

// ---------- XT[b][p][ci] = bf16(s[b][ci] * x[b][ci][p]) ----------
__global__ void k_prepx(const float* __restrict__ x, const float* __restrict__ s,
                        unsigned short* __restrict__ XT) {
    int blk = blockIdx.x;                 // 16b * 16pt * 8ct = 2048
    int b = blk >> 7, pt = (blk >> 3) & 15, ct = blk & 7;
    int p0 = pt * 64, ci0 = ct * 64;
    __shared__ float xt[64][65];
    __shared__ float ss[64];
    int t = threadIdx.x;
    if (t < 64) ss[t] = s[b * CIN + ci0 + t];
    const float* xb = x + ((size_t)(b * CIN + ci0)) * 1024 + p0;
#pragma unroll
    for (int rr = 0; rr < 4; ++rr) {
        int i = rr * 16 + (t >> 4), j = (t & 15) * 4;
        float4 v = *(const float4*)(xb + (size_t)i * 1024 + j);
        xt[i][j] = v.x; xt[i][j + 1] = v.y; xt[i][j + 2] = v.z; xt[i][j + 3] = v.w;
    }
    __syncthreads();
    unsigned short* xo = XT + ((size_t)(b * 1024 + p0)) * CIN + ci0;
#pragma unroll
    for (int rr = 0; rr < 4; ++rr) {
        int jj = rr * 16 + (t >> 4);
        int c4 = (t & 15) * 4;
        ushort4 o;
        o.x = f2bf(xt[c4][jj] * ss[c4]);
        o.y = f2bf(xt[c4 + 1][jj] * ss[c4 + 1]);
        o.z = f2bf(xt[c4 + 2][jj] * ss[c4 + 2]);
        o.w = f2bf(xt[c4 + 3][jj] * ss[c4 + 3]);
        *(ushort4*)(xo + (size_t)jj * CIN + c4) = o;
    }
}

// ---------- bf16 GEMM: C[4608][Ns] fp16 = A9[4608][512] x XT[Ns][512]^T ----------
// 128M x 256N tile, BK=64, 512 threads (2x4 waves), XOR-swizzled LDS.
__device__ __forceinline__ void gload16(const void* g, void* l) {
    __builtin_amdgcn_global_load_lds(
        (const __attribute__((address_space(1))) void*)g,
        (__attribute__((address_space(3))) void*)l, 16, 0, 0);
}

__device__ __forceinline__ unsigned swz_off(unsigned o) {
    unsigned row = o >> 7, kb = o & 127u;
    return row * 1024u + (kb ^ ((row & 7u) << 4));
}

__launch_bounds__(512, 4)
__global__ void k_gemm(const unsigned short* __restrict__ A9,
                       const unsigned short* __restrict__ XT,
                       _Float16* __restrict__ C, int Ns) {
    __shared__ unsigned short smem[24576];   // A: 16KB @0, B: 32KB @16384
    const int t = threadIdx.x;
    const int bm = blockIdx.x, bn = blockIdx.y;
    const int w = t >> 6, lane = t & 63;
    const int wr = w >> 2, wc = w & 3;

    char* sbase = (char*)smem;
    char* ldsA0 = sbase + w * 1024;
    char* ldsA1 = ldsA0 + 8192;
    char* ldsB0 = sbase + 16384 + w * 1024;
    char* ldsB1 = ldsB0 + 8192;
    char* ldsB2 = ldsB0 + 16384;
    char* ldsB3 = ldsB0 + 24576;

    const char* gA = (const char*)A9 + (size_t)bm * 128 * 1024;
    const char* gB = (const char*)XT + (size_t)bn * 256 * 1024;
    const unsigned to = (unsigned)t * 16u;
    const unsigned oA0 = swz_off(to), oA1 = swz_off(to + 8192u);
    const unsigned oB0 = oA0, oB1 = oA1;
    const unsigned oB2 = swz_off(to + 16384u), oB3 = swz_off(to + 24576u);

    const int lrow = lane & 15;
    const unsigned swz = (unsigned)(lane & 7) << 4;
    const unsigned kg = (unsigned)(lane >> 4) << 4;
    const unsigned offA_s0 = (unsigned)((wr * 64 + lrow) * 128) + (kg ^ swz);
    const unsigned offA_s1 = (unsigned)((wr * 64 + lrow) * 128) + ((64u + kg) ^ swz);
    const unsigned offB_s0 = 16384u + (unsigned)((wc * 64 + lrow) * 128) + (kg ^ swz);
    const unsigned offB_s1 = 16384u + (unsigned)((wc * 64 + lrow) * 128) + ((64u + kg) ^ swz);

    f32x4 acc[4][4];
#pragma unroll
    for (int i = 0; i < 4; ++i)
#pragma unroll
        for (int j = 0; j < 4; ++j) acc[i][j] = (f32x4){0.f, 0.f, 0.f, 0.f};

    for (int it = 0; it < 8; ++it) {          // K = 512, BK = 64
        __syncthreads();
        gload16(gA + oA0, ldsA0);
        gload16(gA + oA1, ldsA1);
        gload16(gB + oB0, ldsB0);
        gload16(gB + oB1, ldsB1);
        gload16(gB + oB2, ldsB2);
        gload16(gB + oB3, ldsB3);
        gA += 128; gB += 128;
        __syncthreads();
        bf16x8 a0[4], a1[4];
#pragma unroll
        for (int mf = 0; mf < 4; ++mf) {
            a0[mf] = *(const bf16x8*)(sbase + offA_s0 + mf * 2048);
            a1[mf] = *(const bf16x8*)(sbase + offA_s1 + mf * 2048);
        }
#pragma unroll
        for (int nf = 0; nf < 4; ++nf) {
            bf16x8 b0 = *(const bf16x8*)(sbase + offB_s0 + nf * 2048);
#pragma unroll
            for (int mf = 0; mf < 4; ++mf)
                acc[mf][nf] = __builtin_amdgcn_mfma_f32_16x16x32_bf16(a0[mf], b0, acc[mf][nf], 0, 0, 0);
            bf16x8 b1 = *(const bf16x8*)(sbase + offB_s1 + nf * 2048);
#pragma unroll
            for (int mf = 0; mf < 4; ++mf)
                acc[mf][nf] = __builtin_amdgcn_mfma_f32_16x16x32_bf16(a1[mf], b1, acc[mf][nf], 0, 0, 0);
        }
    }

    const int mg0 = bm * 128 + wr * 64 + (lane >> 4) * 4;
    const int ng0 = bn * 256 + wc * 64 + lrow;
#pragma unroll
    for (int mf = 0; mf < 4; ++mf)
#pragma unroll
        for (int j = 0; j < 4; ++j) {
            size_t row = (size_t)(mg0 + mf * 16 + j) * (size_t)Ns;
#pragma unroll
            for (int nf = 0; nf < 4; ++nf)
                C[row + ng0 + nf * 16] = (_Float16)acc[mf][nf][j];
        }
}

// ---------- scatter 9 taps -> y (parity classes), separable blur, demod, bias ----------
// y[2a+1][2c+1] = T11[a][c]
// y[2a+1][2c]   = T10[a][c] + T12[a][c-1]
// y[2a][2c+1]   = T01[a][c] + T21[a-1][c]
// y[2a][2c]     = T00[a][c] + T02[a][c-1] + T20[a-1][c] + T22[a-1][c-1]
// Taps staged with zero halo (34x34) -> all reads unconditional.
__global__ void k_scat(const _Float16* __restrict__ C, const float* __restrict__ dmod,
                       const float* __restrict__ bias, float* __restrict__ out,
                       int b0, int Ns) {
    const int blk = blockIdx.x;
    const int bl = blk >> 9, co = blk & 511, b = b0 + bl;
    const int t = threadIdx.x;
    __shared__ __align__(16) char pool[29648];
    _Float16* ctp = (_Float16*)pool;             // 9 planes of 34*34 = 1156
    _Float16* ysh = (_Float16*)(pool + 20808);   // 65 rows x stride 68 (cols = y[-1..65])
    float*    hb  = (float*)pool;                // 67 x 64 (overlaps dead ctp)

    // 1. zero taps (incl. halo) + ysh guard cols
    unsigned* zp = (unsigned*)pool;
    for (int i = t; i < 5202; i += 256) zp[i] = 0u;
    if (t < 130) { int r = t >> 1, c = (t & 1) * 66; ysh[r * 68 + c] = (_Float16)0.f; }
    __syncthreads();

    // 2. load 9 tap planes into padded interiors
    const _Float16* Cb = C + (size_t)(co * 9) * (size_t)Ns + bl * 1024;
    const int px4 = t * 4, liy = px4 >> 5, lix = px4 & 31;
#pragma unroll
    for (int k = 0; k < 9; ++k) {
        ushort4 v = *(const ushort4*)(Cb + (size_t)k * Ns + px4);
        _Float16* dst = ctp + k * 1156 + (liy + 1) * 34 + lix + 1;
        dst[0] = __builtin_bit_cast(_Float16, v.x);
        dst[1] = __builtin_bit_cast(_Float16, v.y);
        dst[2] = __builtin_bit_cast(_Float16, v.z);
        dst[3] = __builtin_bit_cast(_Float16, v.w);
    }
    __syncthreads();

    // 3. build y rows (branch-free parity classes)
    {
        const int a = t >> 3, c0 = t & 7;
        const _Float16* P = ctp;
#pragma unroll
        for (int j = 0; j < 4; ++j) {                       // (odd,odd) 32x32
            int c = c0 + 8 * j;
            ysh[(2 * a + 1) * 68 + 2 * c + 2] = P[4 * 1156 + (a + 1) * 34 + c + 1];
        }
        for (int c = c0; c < 33; c += 8)                    // (odd,even) 32x33
            ysh[(2 * a + 1) * 68 + 2 * c + 1] =
                P[3 * 1156 + (a + 1) * 34 + c + 1] + P[5 * 1156 + (a + 1) * 34 + c];
        for (int aa = a; aa < 33; aa += 32) {               // (even,odd) 33x32
#pragma unroll
            for (int j = 0; j < 4; ++j) {
                int c = c0 + 8 * j;
                ysh[(2 * aa) * 68 + 2 * c + 2] =
                    P[1 * 1156 + (aa + 1) * 34 + c + 1] + P[7 * 1156 + aa * 34 + c + 1];
            }
        }
        for (int aa = a; aa < 33; aa += 32)                 // (even,even) 33x33
            for (int c = c0; c < 33; c += 8)
                ysh[(2 * aa) * 68 + 2 * c + 1] =
                    P[0 * 1156 + (aa + 1) * 34 + c + 1] + P[2 * 1156 + (aa + 1) * 34 + c] +
                    P[6 * 1156 + aa * 34 + c + 1]       + P[8 * 1156 + aa * 34 + c];
    }
    __syncthreads();

    // 4. horizontal blur -> hb rows 1..65 (rows 0,66 zero)
    if (t < 128) { int r = (t >> 6) * 66; hb[r * 64 + (t & 63)] = 0.f; }
    for (int i = t; i < 65 * 64; i += 256) {
        int oy = i >> 6, px = i & 63;
        const _Float16* yr = ysh + oy * 68 + px;
        hb[(oy + 1) * 64 + px] = 0.25f * (float)yr[0] + 0.75f * (float)yr[1] +
                                 0.75f * (float)yr[2] + 0.25f * (float)yr[3];
    }
    __syncthreads();

    // 5. vertical blur + demod + bias
    const float dv = dmod[b * COUT + co];
    const float bv = bias[co];
    const int px = t & 63, py0 = t >> 6;
    float* orow = out + ((size_t)b * COUT + co) * 4096;
#pragma unroll
    for (int j = 0; j < 16; ++j) {
        int py = py0 + 4 * j;
        const float* hc = hb + py * 64 + px;
        float sum = 0.25f * hc[0] + 0.75f * hc[64] + 0.75f * hc[128] + 0.25f * hc[192];
        orow[py * 64 + px] = fmaf(dv, sum, bv);
    }
}

extern "C" void kernel_launch(void* const* d_in, const int* in_sizes, int n_in,
                              void* d_out, int out_size, void* d_ws, size_t ws_size,
                              hipStream_t stream) {
    const float* x      = (const float*)d_in[0];
    const float* w      = (const float*)d_in[1];
    const float* weight = (const float*)d_in[2];
    const float* bias   = (const float*)d_in[3];
    const float* aw     = (const float*)d_in[4];
    const float* ab     = (const float*)d_in[5];
    float* out = (float*)d_out;

    char* wsb = (char*)d_ws;
    float* s            = (float*)wsb;                         // 32 KB
    float* dmod         = (float*)(wsb + 32768);               // 32 KB
    float* wsq          = (float*)(wsb + 65536);               // 1 MB
    unsigned short* A9  = (unsigned short*)(wsb + 1114112);    // 4.5 MB
    unsigned short* XT  = (unsigned short*)(wsb + 5832704);    // 16 MB
    _Float16* C         = (_Float16*)(wsb + 22609920);
    const size_t cbase  = 22609920;

    size_t avail = ws_size > cbase ? ws_size - cbase : 0;
    int nbc = 16;                                   // batches per chunk
    while (nbc > 1 && (size_t)4608 * 1024 * (size_t)nbc * 2 > avail) nbc >>= 1;

    k_style<<<NB, 512, 0, stream>>>(w, aw, ab, s);
    k_wsq<<<COUT, 512, 0, stream>>>(weight, wsq);
    k_demod<<<NB, 512, 0, stream>>>(s, wsq, dmod);
    k_prepw<<<COUT, 256, 0, stream>>>(weight, A9);
    k_prepx<<<2048, 256, 0, stream>>>(x, s, XT);

    const int Ns = nbc * 1024;
    for (int bb = 0; bb < NB; bb += nbc) {
        k_gemm<<<dim3(36, nbc * 4), 512, 0, stream>>>(A9, XT + (size_t)bb * 1024 * CIN, C, Ns);
        k_scat<<<nbc * 512, 256, 0, stream>>>(C, dmod, bias, out, bb, Ns);
    }
}